// Round 6
// baseline (234.252 us; speedup 1.0000x reference)
//
#include <hip/hip_runtime.h>
#include <hip/hip_bf16.h>

#define SPAT 32768   // 32*32*32
#define BATCH 2
#define GN_EPS 1e-5f

__device__ __forceinline__ void fma4(float4& a, const float4& v, float w) {
    a.x = fmaf(v.x, w, a.x); a.y = fmaf(v.y, w, a.y);
    a.z = fmaf(v.z, w, a.z); a.w = fmaf(v.w, w, a.w);
}

// Decode XCD-aware swizzled 1D block id.
// Chunks: 64 (sp,b) pairs of 1024 floats; chunk's home XCD = (sp+32b) & 7.
// bid = xcd + 8*(og + OG*pair)  ->  all og for one chunk share bid%8 (same XCD).
template <int OG>
__device__ __forceinline__ void decode_swz(int bid, int& og, int& b, int& s) {
    int xcd = bid & 7;
    int rest = bid >> 3;
    og = rest % OG;
    int pair = rest / OG;            // 0..7
    int spb = pair * 8 + xcd;        // 0..63
    b = spb >> 5;
    s = (spb & 31) * 1024 + threadIdx.x * 4;
}

// ---------------- pointwise conv: 8 output channels x float4 spatial ----------------
// grid: OG*64 blocks (1D, swizzled), block 256
template <int CIN, int COUT, bool RELU, bool AFF>
__global__ __launch_bounds__(256) void k_pw(
    const float* __restrict__ in, const float* __restrict__ w,
    const float* __restrict__ sc, const float* __restrict__ bi,
    float* __restrict__ out)
{
    constexpr int OG = COUT / 8;
    int og, b, s;
    decode_swz<OG>(blockIdx.x, og, b, s);
    int o0 = og * 8;
    const float* ip = in + (size_t)b * CIN * SPAT + s;
    float4 acc[8];
#pragma unroll
    for (int i = 0; i < 8; ++i) acc[i] = {0, 0, 0, 0};
#pragma unroll 4
    for (int c = 0; c < CIN; ++c) {
        float4 v = *(const float4*)(ip + (size_t)c * SPAT);
#pragma unroll
        for (int i = 0; i < 8; ++i)
            fma4(acc[i], v, w[(o0 + i) * CIN + c]);
    }
#pragma unroll
    for (int i = 0; i < 8; ++i) {
        int o = o0 + i;
        float scale = AFF ? sc[o] : 1.f;
        float shift = bi[o];
        float4 r = acc[i];
        r.x = r.x * scale + shift; r.y = r.y * scale + shift;
        r.z = r.z * scale + shift; r.w = r.w * scale + shift;
        if (RELU) {
            r.x = fmaxf(r.x, 0.f); r.y = fmaxf(r.y, 0.f);
            r.z = fmaxf(r.z, 0.f); r.w = fmaxf(r.w, 0.f);
        }
        *(float4*)(out + ((size_t)b * COUT + o) * SPAT + s) = r;
    }
}

// ---------------- cv4 (32->216) + bias + fused GN partial stats ----------------
// grid: 27*64 blocks (1D, swizzled), block 256
__global__ __launch_bounds__(256) void k_cv4(
    const float* __restrict__ in, const float* __restrict__ w,
    const float* __restrict__ bi, float* __restrict__ out,
    float* __restrict__ partial)
{
    int og, b, s;
    decode_swz<27>(blockIdx.x, og, b, s);
    int sp = s >> 10;
    int o0 = og * 8;
    const float* ip = in + (size_t)b * 32 * SPAT + s;
    float4 acc[8];
#pragma unroll
    for (int i = 0; i < 8; ++i) acc[i] = {0, 0, 0, 0};
#pragma unroll 4
    for (int c = 0; c < 32; ++c) {
        float4 v = *(const float4*)(ip + (size_t)c * SPAT);
#pragma unroll
        for (int i = 0; i < 8; ++i)
            fma4(acc[i], v, w[(o0 + i) * 32 + c]);
    }
    float sums[8], sss[8];
#pragma unroll
    for (int i = 0; i < 8; ++i) {
        int o = o0 + i;
        float shift = bi[o];
        float4 r = acc[i];
        r.x += shift; r.y += shift; r.z += shift; r.w += shift;
        *(float4*)(out + ((size_t)b * 216 + o) * SPAT + s) = r;
        sums[i] = r.x + r.y + r.z + r.w;
        sss[i]  = r.x * r.x + r.y * r.y + r.z * r.z + r.w * r.w;
    }
#pragma unroll
    for (int off = 32; off > 0; off >>= 1) {
#pragma unroll
        for (int i = 0; i < 8; ++i) {
            sums[i] += __shfl_down(sums[i], off, 64);
            sss[i]  += __shfl_down(sss[i],  off, 64);
        }
    }
    __shared__ float sh[4][8][2];
    int wave = threadIdx.x >> 6, lane = threadIdx.x & 63;
    if (lane == 0) {
#pragma unroll
        for (int i = 0; i < 8; ++i) {
            sh[wave][i][0] = sums[i];
            sh[wave][i][1] = sss[i];
        }
    }
    __syncthreads();
    if (threadIdx.x < 8) {
        int i = threadIdx.x;
        float s0 = sh[0][i][0] + sh[1][i][0] + sh[2][i][0] + sh[3][i][0];
        float s1 = sh[0][i][1] + sh[1][i][1] + sh[2][i][1] + sh[3][i][1];
        int o = o0 + i;
        int idx = ((b * 216 + o) * 32 + sp) * 2;
        partial[idx + 0] = s0;
        partial[idx + 1] = s1;
    }
}

// ---------------- GN stats stage 2: reduce 27*32 partials per (b,g) ----------------
__global__ __launch_bounds__(256) void k_gn_stats2(
    const float* __restrict__ partial, float* __restrict__ stats)
{
    int bg = blockIdx.x;
    int b = bg >> 3, g = bg & 7;
    float sum = 0.f, ss = 0.f;
    for (int i = threadIdx.x; i < 27 * 32; i += 256) {
        int o = g * 27 + (i >> 5);
        int xb = i & 31;
        int idx = ((b * 216 + o) * 32 + xb) * 2;
        sum += partial[idx + 0];
        ss  += partial[idx + 1];
    }
    __shared__ float sh[512];
    sh[threadIdx.x] = sum; sh[256 + threadIdx.x] = ss;
    __syncthreads();
    for (int off = 128; off > 0; off >>= 1) {
        if (threadIdx.x < off) {
            sh[threadIdx.x] += sh[threadIdx.x + off];
            sh[256 + threadIdx.x] += sh[256 + threadIdx.x + off];
        }
        __syncthreads();
    }
    if (threadIdx.x == 0) {
        stats[bg * 2 + 0] = sh[0];
        stats[bg * 2 + 1] = sh[256];
    }
}

// ---------------- SKA: group-major, quad-vectorized, shuffle wrap ----------------
// grid: (SPAT/1024, 8 groups, B), block 256.
__global__ __launch_bounds__(256) void k_ska(
    const float* __restrict__ x, const float* __restrict__ wk,
    const float* __restrict__ stats,
    const float* __restrict__ gn_g, const float* __restrict__ gn_b,
    const float* __restrict__ bn_s, const float* __restrict__ bn_b,
    float* __restrict__ y)
{
    int q = blockIdx.x * 256 + threadIdx.x;
    int s = q * 4;
    int g = blockIdx.y, b = blockIdx.z;
    int bg = b * 8 + g;
    const float N = 27.f * (float)SPAT;
    float mu  = stats[bg * 2 + 0] / N;
    float var = stats[bg * 2 + 1] / N - mu * mu;
    float inv = rsqrtf(var + GN_EPS);
    int d = s >> 10, h = (s >> 5) & 31, w0 = s & 31;
    int lane = threadIdx.x & 63;
    int xl_src = (lane & 56) | ((lane + 7) & 7);
    int xr_src = (lane & 56) | ((lane + 1) & 7);
    const float* xg = x + ((size_t)(b * 64 + g * 8)) * SPAT;
    const float* wp = wk + ((size_t)(b * 216 + g * 27)) * SPAT + s;

    float4 acc[8];
    float4 xc[8];
#pragma unroll
    for (int c = 0; c < 8; ++c) acc[c] = {0, 0, 0, 0};

#pragma unroll
    for (int kd = 0; kd < 3; ++kd) {
        int zd = (d + kd + 31) & 31;
#pragma unroll
        for (int kh = 0; kh < 3; ++kh) {
            int zh = (h + kh + 31) & 31;
            int kbase = (kd * 3 + kh) * 3;
            float wn[3][4];
#pragma unroll
            for (int kw = 0; kw < 3; ++kw) {
                int kk = kbase + kw;
                float4 wq = *(const float4*)(wp + (size_t)kk * SPAT);
                float gg = gn_g[g * 27 + kk], gb = gn_b[g * 27 + kk];
                wn[kw][0] = (wq.x - mu) * inv * gg + gb;
                wn[kw][1] = (wq.y - mu) * inv * gg + gb;
                wn[kw][2] = (wq.z - mu) * inv * gg + gb;
                wn[kw][3] = (wq.w - mu) * inv * gg + gb;
            }
            int rowoff = zd * 1024 + zh * 32;
            bool center = (kd == 1) && (kh == 1);
#pragma unroll
            for (int c = 0; c < 8; ++c) {
                float4 m = *(const float4*)(xg + (size_t)c * SPAT + rowoff + w0);
                if (center) xc[c] = m;
                float xl = __shfl(m.w, xl_src, 64);
                float xr = __shfl(m.x, xr_src, 64);
                float win[6] = {xl, m.x, m.y, m.z, m.w, xr};
#pragma unroll
                for (int kw = 0; kw < 3; ++kw) {
                    acc[c].x = fmaf(win[0 + kw], wn[kw][0], acc[c].x);
                    acc[c].y = fmaf(win[1 + kw], wn[kw][1], acc[c].y);
                    acc[c].z = fmaf(win[2 + kw], wn[kw][2], acc[c].z);
                    acc[c].w = fmaf(win[3 + kw], wn[kw][3], acc[c].w);
                }
            }
        }
    }
#pragma unroll
    for (int c = 0; c < 8; ++c) {
        int ch = g * 8 + c;
        float bs = bn_s[ch], bb = bn_b[ch];
        float4 r;
        r.x = acc[c].x * bs + bb + xc[c].x;
        r.y = acc[c].y * bs + bb + xc[c].y;
        r.z = acc[c].z * bs + bb + xc[c].z;
        r.w = acc[c].w * bs + bb + xc[c].w;
        *(float4*)(y + ((size_t)(b * 64 + ch)) * SPAT + s) = r;
    }
}

// ---------------- depthwise 5x5x5, zero pad 2, + affine, LDS-tiled ----------------
__global__ __launch_bounds__(256) void k_dw5(
    const float* __restrict__ in, const float* __restrict__ w2,
    const float* __restrict__ s2, const float* __restrict__ b2,
    float* __restrict__ out)
{
    __shared__ float lds[8 * 36 * 40];           // 46,080 B
    int tid = threadIdx.x;
    int d0 = blockIdx.x * 4;
    int c = blockIdx.y, b = blockIdx.z;
    const float* ip = in + ((size_t)(b * 32 + c)) * SPAT;

    float4 z = {0, 0, 0, 0};
    for (int i = tid; i < 8 * 36 * 40 / 4; i += 256)
        ((float4*)lds)[i] = z;
    __syncthreads();
    for (int i = tid; i < 8 * 256; i += 256) {
        int p = i >> 8, rem = i & 255;
        int r = rem >> 3, c4 = (rem & 7) * 4;
        int d = d0 - 2 + p;
        if (d >= 0 && d < 32) {
            float4 v = *(const float4*)(ip + d * 1024 + r * 32 + c4);
            *(float4*)&lds[p * 1440 + (r + 2) * 40 + (c4 + 4)] = v;
        }
    }
    __syncthreads();

    float scl = s2[c], shf = b2[c];
    const float* wt = w2 + c * 125;
#pragma unroll
    for (int k = 0; k < 4; ++k) {
        int j = tid + k * 256;
        int pd = j >> 8, rem = j & 255;
        int hr = rem >> 3, w4 = (rem & 7) * 4;
        float4 acc = {0, 0, 0, 0};
#pragma unroll
        for (int kd = 0; kd < 5; ++kd) {
            const float* pl = &lds[(pd + kd) * 1440];
#pragma unroll
            for (int kh = 0; kh < 5; ++kh) {
                const float* row = pl + (hr + kh) * 40 + w4;
                float4 r0 = *(const float4*)(row);
                float4 r1 = *(const float4*)(row + 4);
                float4 r2 = *(const float4*)(row + 8);
                float win[12] = {r0.x, r0.y, r0.z, r0.w,
                                 r1.x, r1.y, r1.z, r1.w,
                                 r2.x, r2.y, r2.z, r2.w};
#pragma unroll
                for (int kw = 0; kw < 5; ++kw) {
                    float wv = wt[kd * 25 + kh * 5 + kw];
                    acc.x = fmaf(wv, win[2 + 0 + kw], acc.x);
                    acc.y = fmaf(wv, win[2 + 1 + kw], acc.y);
                    acc.z = fmaf(wv, win[2 + 2 + kw], acc.z);
                    acc.w = fmaf(wv, win[2 + 3 + kw], acc.w);
                }
            }
        }
        acc.x = acc.x * scl + shf; acc.y = acc.y * scl + shf;
        acc.z = acc.z * scl + shf; acc.w = acc.w * scl + shf;
        *(float4*)(out + ((size_t)(b * 32 + c)) * SPAT
                   + (d0 + pd) * 1024 + hr * 32 + w4) = acc;
    }
}

// ---------------- pw2 (128->64) + affine + residual -> out, swizzled ----------------
__global__ __launch_bounds__(256) void k_pw2_out(
    const float* __restrict__ f1, const float* __restrict__ w,
    const float* __restrict__ sc, const float* __restrict__ bi,
    const float* __restrict__ yres, float* __restrict__ out)
{
    int og, b, s;
    decode_swz<8>(blockIdx.x, og, b, s);
    int o0 = og * 8;
    const float* ip = f1 + (size_t)b * 128 * SPAT + s;
    float4 acc[8];
#pragma unroll
    for (int i = 0; i < 8; ++i) acc[i] = {0, 0, 0, 0};
#pragma unroll 4
    for (int c = 0; c < 128; ++c) {
        float4 v = *(const float4*)(ip + (size_t)c * SPAT);
#pragma unroll
        for (int i = 0; i < 8; ++i)
            fma4(acc[i], v, w[(o0 + i) * 128 + c]);
    }
#pragma unroll
    for (int i = 0; i < 8; ++i) {
        int o = o0 + i;
        float scale = sc[o], shift = bi[o];
        float4 yv = *(const float4*)(yres + ((size_t)(b * 64 + o)) * SPAT + s);
        float4 r = acc[i];
        r.x = r.x * scale + shift + yv.x;
        r.y = r.y * scale + shift + yv.y;
        r.z = r.z * scale + shift + yv.z;
        r.w = r.w * scale + shift + yv.w;
        *(float4*)(out + ((size_t)(b * 64 + o)) * SPAT + s) = r;
    }
}

extern "C" void kernel_launch(void* const* d_in, const int* in_sizes, int n_in,
                              void* d_out, int out_size, void* d_ws, size_t ws_size,
                              hipStream_t stream)
{
    const float* x     = (const float*)d_in[0];
    const float* w1    = (const float*)d_in[1];
    const float* s1    = (const float*)d_in[2];
    const float* b1    = (const float*)d_in[3];
    const float* w2    = (const float*)d_in[4];
    const float* s2    = (const float*)d_in[5];
    const float* b2    = (const float*)d_in[6];
    const float* w3    = (const float*)d_in[7];
    const float* s3    = (const float*)d_in[8];
    const float* b3    = (const float*)d_in[9];
    const float* w4    = (const float*)d_in[10];
    const float* b4    = (const float*)d_in[11];
    const float* gn_g  = (const float*)d_in[12];
    const float* gn_b  = (const float*)d_in[13];
    const float* bn_s  = (const float*)d_in[14];
    const float* bn_b  = (const float*)d_in[15];
    const float* pw1_w = (const float*)d_in[16];
    const float* pw1_s = (const float*)d_in[17];
    const float* pw1_b = (const float*)d_in[18];
    const float* pw2_w = (const float*)d_in[19];
    const float* pw2_s = (const float*)d_in[20];
    const float* pw2_b = (const float*)d_in[21];

    // Overlapped workspace (~73.6 MB):
    //   region A: [a1 | a2] during LKP, then y during SKA/FFN
    //   region B: wk during cv4..ska, then f1 during FFN
    float* ws    = (float*)d_ws;
    float* a1    = ws;                                   // 2*32*S
    float* a2    = a1 + (size_t)BATCH * 32 * SPAT;       // 2*32*S
    float* yb    = ws;                                   // 2*64*S (over a1+a2)
    float* wkb   = ws + (size_t)BATCH * 64 * SPAT;       // 2*216*S
    float* f1    = wkb;                                  // 2*128*S (over wk)
    float* part  = wkb + (size_t)BATCH * 216 * SPAT;     // 2*216*32*2
    float* stats = part + BATCH * 216 * 32 * 2;          // 32

    dim3 blk(256);
    // cv1 + BN + ReLU : 64 -> 32  (OG=4, grid 256)
    k_pw<64, 32, true, true><<<dim3(4 * 64), blk, 0, stream>>>(x, w1, s1, b1, a1);
    // dw 5^3 + BN (LDS-tiled)
    k_dw5<<<dim3(8, 32, BATCH), blk, 0, stream>>>(a1, w2, s2, b2, a2);
    // cv3 + BN + ReLU : 32 -> 32  (OG=4)
    k_pw<32, 32, true, true><<<dim3(4 * 64), blk, 0, stream>>>(a2, w3, s3, b3, a1);
    // cv4 + bias + fused GN partial stats : 32 -> 216  (OG=27)
    k_cv4<<<dim3(27 * 64), blk, 0, stream>>>(a1, w4, b4, wkb, part);
    // GN stats stage 2
    k_gn_stats2<<<dim3(16), blk, 0, stream>>>(part, stats);
    // SKA + BN + residual -> y
    k_ska<<<dim3(SPAT / 1024, 8, BATCH), blk, 0, stream>>>(
        x, wkb, stats, gn_g, gn_b, bn_s, bn_b, yb);
    // pw1 + BN + ReLU : 64 -> 128  (OG=16)
    k_pw<64, 128, true, true><<<dim3(16 * 64), blk, 0, stream>>>(
        yb, pw1_w, pw1_s, pw1_b, f1);
    // pw2 + BN + residual -> out  (OG=8)
    k_pw2_out<<<dim3(8 * 64), blk, 0, stream>>>(
        f1, pw2_w, pw2_s, pw2_b, yb, (float*)d_out);
}